// Round 11
// baseline (369.686 us; speedup 1.0000x reference)
//
#include <hip/hip_runtime.h>

#define Kst 256
#define Dd 256
#define Vv 50000
#define VPAD 50176
#define Tt 512
#define Bb 256
#define KP1 257
#define MD 512
#define NROWS (KP1*KP1)   // 66049
#define EPSf 1e-5f

#define VB2 196           // vocab blocks (256 v each)
#define VB3 (VB2*4)       // per-wave lse partials per k row

typedef __attribute__((ext_vector_type(8))) short short8;
typedef __attribute__((ext_vector_type(4))) short short4v;
typedef __attribute__((ext_vector_type(4))) float f32x4;
typedef __attribute__((ext_vector_type(4))) unsigned u32x4;
typedef __attribute__((ext_vector_type(2))) unsigned u32x2;

__device__ __forceinline__ unsigned short f2bf(float f) {
    unsigned u = __builtin_bit_cast(unsigned, f);
    unsigned r = (u + 0x7fffu + ((u >> 16) & 1u)) >> 16;
    return (unsigned short)r;
}
__device__ __forceinline__ float bf2f(unsigned short u) {
    return __builtin_bit_cast(float, ((unsigned)u) << 16);
}
__device__ __forceinline__ unsigned bfpack(float lo, float hi) {
    return __builtin_amdgcn_perm(__builtin_bit_cast(unsigned, hi),
                                 __builtin_bit_cast(unsigned, lo), 0x07060302u);
}

// ---------------- K_pre: fused preprocessing ----------------
__global__ __launch_bounds__(256) void k_pre(
    const float* __restrict__ lembs, const float* __restrict__ em_W,
    const float* __restrict__ em_bias, const float* __restrict__ em_g,
    const float* __restrict__ em_beta, unsigned short* __restrict__ h_bf,
    const float* __restrict__ tlembs, const float* __restrict__ tm_W,
    float* __restrict__ P0, float* __restrict__ P1,
    const float* __restrict__ td_W, const float* __restrict__ tn_g,
    const float* __restrict__ tn_beta, const float* __restrict__ td_b,
    unsigned short* __restrict__ tdwg_bf, float* __restrict__ Gt,
    float* __restrict__ Bt)
{
    int bid = blockIdx.x;
    int tid = threadIdx.x;
    if (bid < 256) {
        int k = bid, d = tid;
        __shared__ float lrow[Dd];
        __shared__ float red[256];
        lrow[d] = lembs[k*Dd + d];
        __syncthreads();
        float acc = em_bias[d];
        const float4* w4 = (const float4*)(em_W + (size_t)d*Dd);
        for (int j4 = 0; j4 < Dd/4; ++j4) {
            float4 w = w4[j4];
            acc += w.x*lrow[4*j4] + w.y*lrow[4*j4+1] + w.z*lrow[4*j4+2] + w.w*lrow[4*j4+3];
        }
        float val = lrow[d] + fmaxf(acc, 0.f);
        red[d] = val; __syncthreads();
        for (int s = 128; s > 0; s >>= 1) { if (d < s) red[d] += red[d+s]; __syncthreads(); }
        float mu = red[0] * (1.f/Dd);
        __syncthreads();
        float c = val - mu;
        red[d] = c*c; __syncthreads();
        for (int s = 128; s > 0; s >>= 1) { if (d < s) red[d] += red[d+s]; __syncthreads(); }
        float rstd = rsqrtf(red[0] * (1.f/Dd) + EPSf);
        h_bf[k*Dd + d] = f2bf(c * rstd * em_g[d] + em_beta[d]);
    } else if (bid < 513) {
        int i = bid - 256;
        __shared__ float tl[Dd];
        if (tid < Dd) tl[tid] = tlembs[i*Dd + tid];
        __syncthreads();
        for (int half = 0; half < 2; ++half) {
            int j = tid + half*256;
            float a0 = 0.f, a1 = 0.f;
            const float4* w4 = (const float4*)(tm_W + (size_t)j*MD);
            for (int l4 = 0; l4 < 64; ++l4) {
                float4 w = w4[l4];
                a0 += w.x*tl[4*l4] + w.y*tl[4*l4+1] + w.z*tl[4*l4+2] + w.w*tl[4*l4+3];
            }
            for (int l4 = 64; l4 < 128; ++l4) {
                float4 w = w4[l4];
                int l = 4*l4 - 256;
                a1 += w.x*tl[l] + w.y*tl[l+1] + w.z*tl[l+2] + w.w*tl[l+3];
            }
            P0[(size_t)i*MD + j] = a0;
            P1[(size_t)i*MD + j] = a1;
        }
    } else {
        int wv = tid >> 6, lane = tid & 63;
        int c = (bid - 513)*4 + wv;
        const float4* w4 = (const float4*)(td_W + (size_t)c*MD);
        const float4* g4 = (const float4*)tn_g;
        const float4* b4 = (const float4*)tn_beta;
        float sg = 0.f, sb = 0.f;
        short8 o;
        #pragma unroll
        for (int u = 0; u < 2; ++u) {
            int j4 = lane*2 + u;
            float4 w = w4[j4], g = g4[j4], bt = b4[j4];
            sg += w.x*g.x + w.y*g.y + w.z*g.z + w.w*g.w;
            sb += w.x*bt.x + w.y*bt.y + w.z*bt.z + w.w*bt.w;
            o[u*4+0] = (short)f2bf(w.x*g.x);
            o[u*4+1] = (short)f2bf(w.y*g.y);
            o[u*4+2] = (short)f2bf(w.z*g.z);
            o[u*4+3] = (short)f2bf(w.w*g.w);
        }
        *(short8*)(tdwg_bf + (size_t)c*MD + lane*8) = o;
        #pragma unroll
        for (int dd = 32; dd > 0; dd >>= 1) {
            sg += __shfl_xor(sg, dd);
            sb += __shfl_xor(sb, dd);
        }
        if (lane == 0) { Gt[c] = sg; Bt[c] = sb + td_b[c]; }
    }
}

// ---------------- K_em (MFMA): C[k][v] = h @ dec_W^T, f32 A-load + in-reg pack ----------------
__global__ __launch_bounds__(256) void k_em_mfma4(
    const float* __restrict__ dec_W, const float* __restrict__ dec_b,
    const unsigned short* __restrict__ h_bf, float* __restrict__ part,
    unsigned short* __restrict__ E2)
{
    int vb = blockIdx.x, kg = blockIdx.y;
    int tid = threadIdx.x, lane = tid & 63, wv = tid >> 6;
    int l15 = lane & 15, q = lane >> 4;
    __shared__ short hs[64][264];

    {
        int row = tid >> 2, c0 = (tid & 3) * 64;
        const short8* src = (const short8*)(h_bf + (size_t)(kg*64 + row)*Dd + c0);
        #pragma unroll
        for (int u = 0; u < 8; ++u)
            *(short8*)&hs[row][c0 + u*8] = src[u];
    }
    __syncthreads();

    const float* bptr[4];
    int vcol[4]; bool vok[4];
    #pragma unroll
    for (int ct = 0; ct < 4; ++ct) {
        int v = vb*256 + wv*64 + ct*16 + l15;
        vok[ct] = (v < Vv);
        if (v > Vv-1) v = Vv-1;
        vcol[ct] = v;
        bptr[ct] = dec_W + (size_t)v*Dd + q*8;
    }
    f32x4 acc[4][4];
    #pragma unroll
    for (int mt = 0; mt < 4; ++mt)
        #pragma unroll
        for (int ct = 0; ct < 4; ++ct)
            acc[mt][ct] = (f32x4){0.f,0.f,0.f,0.f};

    for (int ks = 0; ks < 8; ++ks) {
        short8 a[4], b[4];
        #pragma unroll
        for (int ct = 0; ct < 4; ++ct) {
            float4 f0 = *(const float4*)(bptr[ct] + ks*32);
            float4 f1 = *(const float4*)(bptr[ct] + ks*32 + 4);
            u32x4 pk;
            pk.x = bfpack(f0.x, f0.y);
            pk.y = bfpack(f0.z, f0.w);
            pk.z = bfpack(f1.x, f1.y);
            pk.w = bfpack(f1.z, f1.w);
            b[ct] = __builtin_bit_cast(short8, pk);
        }
        #pragma unroll
        for (int mt = 0; mt < 4; ++mt)
            a[mt] = *(const short8*)&hs[mt*16 + l15][ks*32 + q*8];
        #pragma unroll
        for (int mt = 0; mt < 4; ++mt)
            #pragma unroll
            for (int ct = 0; ct < 4; ++ct)
                acc[mt][ct] = __builtin_amdgcn_mfma_f32_16x16x32_bf16(a[mt], b[ct], acc[mt][ct], 0,0,0);
    }

    #pragma unroll
    for (int ct = 0; ct < 4; ++ct) {
        if (vok[ct]) {
            float db = dec_b[vcol[ct]];
            #pragma unroll
            for (int mt = 0; mt < 4; ++mt)
                #pragma unroll
                for (int reg = 0; reg < 4; ++reg)
                    acc[mt][ct][reg] += db;
        } else {
            #pragma unroll
            for (int mt = 0; mt < 4; ++mt)
                #pragma unroll
                for (int reg = 0; reg < 4; ++reg)
                    acc[mt][ct][reg] = -1e30f;
        }
    }
    // direct coalesced E2 store
    #pragma unroll
    for (int mt = 0; mt < 4; ++mt) {
        #pragma unroll
        for (int reg = 0; reg < 4; ++reg) {
            int k = kg*64 + mt*16 + q*4 + reg;
            unsigned short* dst = E2 + (size_t)k*VPAD + vb*256 + wv*64;
            #pragma unroll
            for (int ct = 0; ct < 4; ++ct)
                if (vok[ct]) dst[ct*16 + l15] = f2bf(acc[mt][ct][reg]);
        }
    }
    // per-wave lse partials
    #pragma unroll
    for (int mt = 0; mt < 4; ++mt) {
        #pragma unroll
        for (int reg = 0; reg < 4; ++reg) {
            float m = fmaxf(fmaxf(acc[mt][0][reg], acc[mt][1][reg]),
                            fmaxf(acc[mt][2][reg], acc[mt][3][reg]));
            m = fmaxf(m, __shfl_xor(m, 1));
            m = fmaxf(m, __shfl_xor(m, 2));
            m = fmaxf(m, __shfl_xor(m, 4));
            m = fmaxf(m, __shfl_xor(m, 8));
            float s = __expf(acc[mt][0][reg] - m) + __expf(acc[mt][1][reg] - m)
                    + __expf(acc[mt][2][reg] - m) + __expf(acc[mt][3][reg] - m);
            s += __shfl_xor(s, 1);
            s += __shfl_xor(s, 2);
            s += __shfl_xor(s, 4);
            s += __shfl_xor(s, 8);
            if (l15 == 0) {
                int k = kg*64 + mt*16 + q*4 + reg;
                part[((size_t)k*VB3 + vb*4 + wv)*2]     = m;
                part[((size_t)k*VB3 + vb*4 + wv)*2 + 1] = s;
            }
        }
    }
}

// ---------------- K_comb: combine partials -> lse_em[k] ----------------
__global__ __launch_bounds__(64) void k_em_comb3(
    const float* __restrict__ part, float* __restrict__ lse_em)
{
    int k = blockIdx.x, lane = threadIdx.x;
    float m = -1e30f, s = 0.f;
    for (int vb = lane; vb < VB3; vb += 64) {
        float m2 = part[((size_t)k*VB3+vb)*2], s2 = part[((size_t)k*VB3+vb)*2+1];
        if (m2 > m) { s = s*__expf(m - m2) + s2; m = m2; }
        else          s += s2*__expf(m2 - m);
    }
    #pragma unroll
    for (int d = 1; d < 64; d <<= 1) {
        float mo = __shfl_xor(m, d), so = __shfl_xor(s, d);
        float mn = fmaxf(m, mo);
        s = s*__expf(m - mn) + so*__expf(mo - mn);
        m = mn;
    }
    if (lane == 0) lse_em[k] = m + logf(s);
}

// ---------------- K_trans8: 4-barrier, zero-LDS epilogue, direct Td stores ----------------
__global__ __launch_bounds__(256) void k_trans8(
    const float* __restrict__ tlembs, const float* __restrict__ P0,
    const float* __restrict__ P1, const float* __restrict__ tm_bias,
    const short* __restrict__ tdwg_bf, const float* __restrict__ Gt,
    const float* __restrict__ Bt, float* __restrict__ lse_t,
    unsigned short* __restrict__ Td)
{
    __shared__ short th[32][520];          // 33.3 KB raw v tile (bf16)
    __shared__ float rstat[32][18];
    __shared__ float musig[32][2];
    __shared__ float lsep[4][32][2];       // per-wave (m,s) per row
    int tid = threadIdx.x, lane = tid & 63, wv = tid >> 6;
    int r0 = blockIdx.x * 32;

    // ---- pass 1: coalesced, dependency-free staging of raw v ----
    {
        const float4* bias0 = (const float4*)tm_bias;
        const float4* bias1 = (const float4*)(tm_bias + 256);
        float4 c0 = bias0[lane], c1 = bias1[lane];
        for (int i = 0; i < 8; ++i) {
            int row = wv*8 + i;
            int r = r0 + row; if (r >= NROWS) r = NROWS - 1;
            int i0 = r / KP1, i1 = r - i0*KP1;
            float4 a0 = ((const float4*)(P0 + (size_t)i0*MD))[lane];
            float4 b0 = ((const float4*)(P1 + (size_t)i1*MD))[lane];
            float4 t0 = ((const float4*)(tlembs + (size_t)i0*Dd))[lane];
            float4 a1 = ((const float4*)(P0 + (size_t)i0*MD + 256))[lane];
            float4 b1 = ((const float4*)(P1 + (size_t)i1*MD + 256))[lane];
            float4 t1 = ((const float4*)(tlembs + (size_t)i1*Dd))[lane];
            float v0 = t0.x + fmaxf(a0.x+b0.x+c0.x, 0.f);
            float v1 = t0.y + fmaxf(a0.y+b0.y+c0.y, 0.f);
            float v2 = t0.z + fmaxf(a0.z+b0.z+c0.z, 0.f);
            float v3 = t0.w + fmaxf(a0.w+b0.w+c0.w, 0.f);
            float v4 = t1.x + fmaxf(a1.x+b1.x+c1.x, 0.f);
            float v5 = t1.y + fmaxf(a1.y+b1.y+c1.y, 0.f);
            float v6 = t1.z + fmaxf(a1.z+b1.z+c1.z, 0.f);
            float v7 = t1.w + fmaxf(a1.w+b1.w+c1.w, 0.f);
            u32x2 p0; p0.x = bfpack(v0, v1); p0.y = bfpack(v2, v3);
            u32x2 p1; p1.x = bfpack(v4, v5); p1.y = bfpack(v6, v7);
            *(u32x2*)&th[row][lane*4]       = p0;
            *(u32x2*)&th[row][256 + lane*4] = p1;
        }
    }
    __syncthreads();                       // (1)
    // ---- pass 2: LN stats from LDS ----
    {
        int row = tid & 31, seg = tid >> 5;
        float s = 0.f, ss = 0.f;
        #pragma unroll
        for (int k8 = 0; k8 < 8; ++k8) {
            short8 vv = *(const short8*)&th[row][seg*64 + k8*8];
            #pragma unroll
            for (int e = 0; e < 8; ++e) {
                float f = bf2f((unsigned short)vv[e]);
                s += f; ss += f*f;
            }
        }
        rstat[row][seg]     = s;
        rstat[row][9 + seg] = ss;
    }
    __syncthreads();                       // (2)
    if (tid < 32) {
        float s  = ((rstat[tid][0] + rstat[tid][1]) + (rstat[tid][2] + rstat[tid][3]))
                 + ((rstat[tid][4] + rstat[tid][5]) + (rstat[tid][6] + rstat[tid][7]));
        float ss = ((rstat[tid][9] + rstat[tid][10]) + (rstat[tid][11] + rstat[tid][12]))
                 + ((rstat[tid][13] + rstat[tid][14]) + (rstat[tid][15] + rstat[tid][16]));
        float mu = s * (1.f/MD);
        musig[tid][0] = mu;
        musig[tid][1] = rsqrtf(ss*(1.f/MD) - mu*mu + EPSf);
    }
    __syncthreads();                       // (3)

    // ---- MFMA on raw v with (W*g)^T ----
    int l15 = lane & 15, q = lane >> 4;
    f32x4 acc[2][4];
    #pragma unroll
    for (int rt = 0; rt < 2; ++rt)
        #pragma unroll
        for (int ct = 0; ct < 4; ++ct)
            acc[rt][ct] = (f32x4){0.f, 0.f, 0.f, 0.f};
    const short* tb = tdwg_bf + ((size_t)(wv*64 + l15))*MD + q*8;
    #pragma unroll 4
    for (int ks = 0; ks < 16; ++ks) {
        int ko = ks*32 + q*8;
        short8 a0 = *(const short8*)&th[ 0 + l15][ko];
        short8 a1 = *(const short8*)&th[16 + l15][ko];
        short8 b0 = *(const short8*)(tb + ks*32);
        short8 b1 = *(const short8*)(tb + 16*MD + ks*32);
        short8 b2 = *(const short8*)(tb + 32*MD + ks*32);
        short8 b3 = *(const short8*)(tb + 48*MD + ks*32);
        acc[0][0] = __builtin_amdgcn_mfma_f32_16x16x32_bf16(a0, b0, acc[0][0], 0,0,0);
        acc[1][0] = __builtin_amdgcn_mfma_f32_16x16x32_bf16(a1, b0, acc[1][0], 0,0,0);
        acc[0][1] = __builtin_amdgcn_mfma_f32_16x16x32_bf16(a0, b1, acc[0][1], 0,0,0);
        acc[1][1] = __builtin_amdgcn_mfma_f32_16x16x32_bf16(a1, b1, acc[1][1], 0,0,0);
        acc[0][2] = __builtin_amdgcn_mfma_f32_16x16x32_bf16(a0, b2, acc[0][2], 0,0,0);
        acc[1][2] = __builtin_amdgcn_mfma_f32_16x16x32_bf16(a1, b2, acc[1][2], 0,0,0);
        acc[0][3] = __builtin_amdgcn_mfma_f32_16x16x32_bf16(a0, b3, acc[0][3], 0,0,0);
        acc[1][3] = __builtin_amdgcn_mfma_f32_16x16x32_bf16(a1, b3, acc[1][3], 0,0,0);
    }

    // ---- epilogue: LN affine, direct Td store, per-wave lse, single barrier ----
    float Gc[4], Bc[4];
    #pragma unroll
    for (int ct = 0; ct < 4; ++ct) {
        Gc[ct] = Gt[wv*64 + ct*16 + l15];
        Bc[ct] = Bt[wv*64 + ct*16 + l15];
    }
    #pragma unroll
    for (int rt = 0; rt < 2; ++rt) {
        #pragma unroll
        for (int reg = 0; reg < 4; ++reg) {
            int rw = rt*16 + q*4 + reg;
            float mu = musig[rw][0], rs = musig[rw][1];
            #pragma unroll
            for (int ct = 0; ct < 4; ++ct)
                acc[rt][ct][reg] = rs*(acc[rt][ct][reg] - mu*Gc[ct]) + Bc[ct];
        }
    }
    // direct Td store: 32B segments (16 lanes x 2B), 4 segments per instr (one per q)
    #pragma unroll
    for (int rt = 0; rt < 2; ++rt) {
        #pragma unroll
        for (int reg = 0; reg < 4; ++reg) {
            long r = (long)r0 + rt*16 + q*4 + reg;
            if (r < NROWS) {
                unsigned short* dst = Td + (size_t)r*Kst + wv*64;
                #pragma unroll
                for (int ct = 0; ct < 4; ++ct)
                    dst[ct*16 + l15] = f2bf(acc[rt][ct][reg]);
            }
        }
    }
    // per-wave online (m,s) per row
    #pragma unroll
    for (int rt = 0; rt < 2; ++rt) {
        #pragma unroll
        for (int reg = 0; reg < 4; ++reg) {
            float m = fmaxf(fmaxf(acc[rt][0][reg], acc[rt][1][reg]),
                            fmaxf(acc[rt][2][reg], acc[rt][3][reg]));
            m = fmaxf(m, __shfl_xor(m, 1));
            m = fmaxf(m, __shfl_xor(m, 2));
            m = fmaxf(m, __shfl_xor(m, 4));
            m = fmaxf(m, __shfl_xor(m, 8));
            float s = __expf(acc[rt][0][reg] - m) + __expf(acc[rt][1][reg] - m)
                    + __expf(acc[rt][2][reg] - m) + __expf(acc[rt][3][reg] - m);
            s += __shfl_xor(s, 1);
            s += __shfl_xor(s, 2);
            s += __shfl_xor(s, 4);
            s += __shfl_xor(s, 8);
            if (l15 == 0) {
                int rw = rt*16 + q*4 + reg;
                lsep[wv][rw][0] = m;
                lsep[wv][rw][1] = s;
            }
        }
    }
    __syncthreads();                       // (4)
    if (tid < 32) {
        int r = r0 + tid;
        if (r < NROWS) {
            float m0 = lsep[0][tid][0], m1 = lsep[1][tid][0];
            float m2 = lsep[2][tid][0], m3 = lsep[3][tid][0];
            float mg = fmaxf(fmaxf(m0, m1), fmaxf(m2, m3));
            float s = lsep[0][tid][1]*__expf(m0-mg) + lsep[1][tid][1]*__expf(m1-mg)
                    + lsep[2][tid][1]*__expf(m2-mg) + lsep[3][tid][1]*__expf(m3-mg);
            lse_t[r] = mg + logf(s);
        }
    }
}

// ---------------- K_gather: 2 table lookups per (t,b), one block per t ----------------
__global__ __launch_bounds__(256) void k_gather2(
    const int* __restrict__ x, const int* __restrict__ z,
    const unsigned short* __restrict__ E2, const float* __restrict__ lse_em,
    const unsigned short* __restrict__ Td, const float* __restrict__ lse_t,
    float* __restrict__ out)
{
    int b = threadIdx.x;
    int t = blockIdx.x;
    int zc = z[t*Bb + b];
    int xv = x[t*Bb + b];
    int i0 = (t >= 2) ? z[(t-2)*Bb + b] : Kst;
    int i1 = (t >= 1) ? z[(t-1)*Bb + b] : Kst;
    int lin = i0*KP1 + i1;
    float em = bf2f(E2[(size_t)zc*VPAD + xv]) - lse_em[zc];
    float tr = bf2f(Td[(size_t)lin*Kst + zc]) - lse_t[lin];
    atomicAdd(&out[b], em + tr);
}

extern "C" void kernel_launch(void* const* d_in, const int* in_sizes, int n_in,
                              void* d_out, int out_size, void* d_ws, size_t ws_size,
                              hipStream_t stream)
{
    const int*   x       = (const int*)  d_in[0];
    const int*   z       = (const int*)  d_in[1];
    const float* lembs   = (const float*)d_in[2];
    const float* tlembs  = (const float*)d_in[3];
    const float* dec_W   = (const float*)d_in[4];
    const float* dec_b   = (const float*)d_in[5];
    const float* em_W    = (const float*)d_in[6];
    const float* em_bias = (const float*)d_in[7];
    const float* em_g    = (const float*)d_in[8];
    const float* em_beta = (const float*)d_in[9];
    const float* td_W    = (const float*)d_in[10];
    const float* td_b    = (const float*)d_in[11];
    const float* tm_W    = (const float*)d_in[12];
    const float* tm_bias = (const float*)d_in[13];
    const float* tn_g    = (const float*)d_in[14];
    const float* tn_beta = (const float*)d_in[15];
    float* out = (float*)d_out;

    float* ws     = (float*)d_ws;
    float* P0     = ws;                    // 131584
    float* P1     = P0 + 131584;           // 131584
    float* lse_em = P1 + 131584;           // 256
    float* part   = lse_em + 256;          // 256*784*2 = 401408
    float* lse_t  = part + 401408;         // 66052
    float* Gt     = lse_t + 66052;         // 256
    float* Bt     = Gt + 256;              // 256
    unsigned short* tdwg_bf = (unsigned short*)(Bt + 256);      // 131072 ushort
    unsigned short* h_bf   = tdwg_bf + 131072;                  // 65536 ushort
    unsigned short* E2     = h_bf + 65536;                      // 256*50176 ushort (25.7MB)
    unsigned short* Td     = E2 + (size_t)Kst*VPAD;             // 66049*256 ushort (33.8MB)

    hipMemsetAsync(out, 0, Bb*sizeof(float), stream);
    k_pre<<<577, 256, 0, stream>>>(lembs, em_W, em_bias, em_g, em_beta, h_bf,
                                   tlembs, tm_W, P0, P1,
                                   td_W, tn_g, tn_beta, td_b, tdwg_bf, Gt, Bt);
    k_em_mfma4<<<dim3(VB2, 4), 256, 0, stream>>>(dec_W, dec_b, h_bf, part, E2);
    k_em_comb3<<<Kst, 64, 0, stream>>>(part, lse_em);
    k_trans8<<<(NROWS + 31)/32, 256, 0, stream>>>(tlembs, P0, P1, tm_bias,
                                                  (const short*)tdwg_bf, Gt, Bt,
                                                  lse_t, Td);
    k_gather2<<<Tt, 256, 0, stream>>>(x, z, E2, lse_em, Td, lse_t, out);
}

// Round 12
// 295.527 us; speedup vs baseline: 1.2509x; 1.2509x over previous
//
#include <hip/hip_runtime.h>

#define Kst 256
#define Dd 256
#define Vv 50000
#define VPAD 50176
#define Tt 512
#define Bb 256
#define KP1 257
#define MD 512
#define NROWS (KP1*KP1)   // 66049
#define EPSf 1e-5f

#define VB2 196           // vocab blocks (256 v each)
#define VB3 (VB2*4)       // per-wave lse partials per k row

typedef __attribute__((ext_vector_type(8))) short short8;
typedef __attribute__((ext_vector_type(4))) short short4v;
typedef __attribute__((ext_vector_type(4))) float f32x4;
typedef __attribute__((ext_vector_type(4))) unsigned u32x4;
typedef __attribute__((ext_vector_type(2))) unsigned u32x2;

__device__ __forceinline__ unsigned short f2bf(float f) {
    unsigned u = __builtin_bit_cast(unsigned, f);
    unsigned r = (u + 0x7fffu + ((u >> 16) & 1u)) >> 16;
    return (unsigned short)r;
}
__device__ __forceinline__ float bf2f(unsigned short u) {
    return __builtin_bit_cast(float, ((unsigned)u) << 16);
}
__device__ __forceinline__ unsigned bfpack(float lo, float hi) {
    return __builtin_amdgcn_perm(__builtin_bit_cast(unsigned, hi),
                                 __builtin_bit_cast(unsigned, lo), 0x07060302u);
}

// ---------------- K_hP: MFMA preprocessing ----------------
// bid [0,8):    h = LN(lembs + relu(lembs@em_W^T + em_bias)) -> h_bf   (32 rows/block)
// bid [8,44):   P0/P1 = tlembs @ tm_W[:, half]^T -> f32                (32 rows x 256 cols/block)
// bid [44,108): tdwg = bf16(td_W*g), Gt, Bt                            (4 cols/block)
__global__ __launch_bounds__(256) void k_hP(
    const float* __restrict__ lembs, const float* __restrict__ em_W,
    const float* __restrict__ em_bias, const float* __restrict__ em_g,
    const float* __restrict__ em_beta, unsigned short* __restrict__ h_bf,
    const float* __restrict__ tlembs, const float* __restrict__ tm_W,
    float* __restrict__ P0, float* __restrict__ P1,
    const float* __restrict__ td_W, const float* __restrict__ tn_g,
    const float* __restrict__ tn_beta, const float* __restrict__ td_b,
    unsigned short* __restrict__ tdwg_bf, float* __restrict__ Gt,
    float* __restrict__ Bt)
{
    int bid = blockIdx.x;
    int tid = threadIdx.x, lane = tid & 63, wv = tid >> 6;
    int l15 = lane & 15, q = lane >> 4;

    if (bid >= 44) {
        // ---- tdwg = bf16(td_W * g), Gt = sum g*W, Bt = sum beta*W + td_b ----
        int c = (bid - 44)*4 + wv;
        const float4* w4 = (const float4*)(td_W + (size_t)c*MD);
        const float4* g4 = (const float4*)tn_g;
        const float4* b4 = (const float4*)tn_beta;
        float sg = 0.f, sb = 0.f;
        short8 o;
        #pragma unroll
        for (int u = 0; u < 2; ++u) {
            int j4 = lane*2 + u;
            float4 w = w4[j4], g = g4[j4], bt = b4[j4];
            sg += w.x*g.x + w.y*g.y + w.z*g.z + w.w*g.w;
            sb += w.x*bt.x + w.y*bt.y + w.z*bt.z + w.w*bt.w;
            o[u*4+0] = (short)f2bf(w.x*g.x);
            o[u*4+1] = (short)f2bf(w.y*g.y);
            o[u*4+2] = (short)f2bf(w.z*g.z);
            o[u*4+3] = (short)f2bf(w.w*g.w);
        }
        *(short8*)(tdwg_bf + (size_t)c*MD + lane*8) = o;
        #pragma unroll
        for (int dd = 32; dd > 0; dd >>= 1) {
            sg += __shfl_xor(sg, dd);
            sb += __shfl_xor(sb, dd);
        }
        if (lane == 0) { Gt[c] = sg; Bt[c] = sb + td_b[c]; }
        return;
    }

    __shared__ short ta[32][264];          // A tile bf16 (16.9 KB)
    __shared__ float lsep[4][32][2];
    __shared__ float musig[32][2];

    int job, r0, cb, koff, BK;
    const float* Arow; const float* Brow;
    if (bid < 8) {
        job = 0; r0 = bid*32; cb = 0; koff = 0; BK = Dd;
        Arow = lembs; Brow = em_W;
    } else {
        int b2 = bid - 8;                 // 0..35
        int half = b2 / 18;               // 0 -> P0, 1 -> P1
        int b3 = b2 % 18;
        job = 1 + half;
        r0 = (b3 >> 1) * 32;              // 9 row tiles (last partially OOB)
        cb = (b3 & 1) * 256;
        koff = half * 256; BK = MD;
        Arow = tlembs; Brow = tm_W;
    }

    // ---- stage A tile (32 rows x 256 K) bf16 -> LDS, coalesced ----
    {
        int row = tid >> 3, seg = (tid & 7) * 32;
        int r = r0 + row;
        if (r > 256) r = 256;             // P jobs: clamp OOB rows (stores skipped)
        const float4* s4 = (const float4*)(Arow + (size_t)r*Dd + seg);
        #pragma unroll
        for (int u = 0; u < 4; ++u) {
            float4 f0 = s4[u*2], f1 = s4[u*2+1];
            u32x4 pk;
            pk.x = bfpack(f0.x, f0.y);
            pk.y = bfpack(f0.z, f0.w);
            pk.z = bfpack(f1.x, f1.y);
            pk.w = bfpack(f1.z, f1.w);
            *(short8*)&ta[row][seg + u*8] = __builtin_bit_cast(short8, pk);
        }
    }
    __syncthreads();

    // ---- MFMA: wave wv owns cols [cb + wv*64, +64), K=256 ----
    const float* bptr[4];
    #pragma unroll
    for (int ct = 0; ct < 4; ++ct) {
        int j = cb + wv*64 + ct*16 + l15;
        bptr[ct] = Brow + (size_t)j*BK + koff + q*8;
    }
    f32x4 acc[2][4];
    #pragma unroll
    for (int rt = 0; rt < 2; ++rt)
        #pragma unroll
        for (int ct = 0; ct < 4; ++ct)
            acc[rt][ct] = (f32x4){0.f,0.f,0.f,0.f};
    for (int ks = 0; ks < 8; ++ks) {
        short8 a0 = *(const short8*)&ta[ 0 + l15][ks*32 + q*8];
        short8 a1 = *(const short8*)&ta[16 + l15][ks*32 + q*8];
        short8 b[4];
        #pragma unroll
        for (int ct = 0; ct < 4; ++ct) {
            float4 f0 = *(const float4*)(bptr[ct] + ks*32);
            float4 f1 = *(const float4*)(bptr[ct] + ks*32 + 4);
            u32x4 pk;
            pk.x = bfpack(f0.x, f0.y);
            pk.y = bfpack(f0.z, f0.w);
            pk.z = bfpack(f1.x, f1.y);
            pk.w = bfpack(f1.z, f1.w);
            b[ct] = __builtin_bit_cast(short8, pk);
        }
        #pragma unroll
        for (int ct = 0; ct < 4; ++ct) {
            acc[0][ct] = __builtin_amdgcn_mfma_f32_16x16x32_bf16(a0, b[ct], acc[0][ct], 0,0,0);
            acc[1][ct] = __builtin_amdgcn_mfma_f32_16x16x32_bf16(a1, b[ct], acc[1][ct], 0,0,0);
        }
    }

    if (job != 0) {
        // ---- P store f32 (64B segments per ct) ----
        float* Pd = (job == 1) ? P0 : P1;
        #pragma unroll
        for (int rt = 0; rt < 2; ++rt) {
            #pragma unroll
            for (int reg = 0; reg < 4; ++reg) {
                int r = r0 + rt*16 + q*4 + reg;
                if (r < KP1) {
                    float* dst = Pd + (size_t)r*MD + cb + wv*64;
                    #pragma unroll
                    for (int ct = 0; ct < 4; ++ct)
                        dst[ct*16 + l15] = acc[rt][ct][reg];
                }
            }
        }
        return;
    }

    // ---- job 0: residual + relu, LN across 4 waves, h_bf store ----
    float bias_c[4];
    #pragma unroll
    for (int ct = 0; ct < 4; ++ct)
        bias_c[ct] = em_bias[wv*64 + ct*16 + l15];
    #pragma unroll
    for (int rt = 0; rt < 2; ++rt) {
        #pragma unroll
        for (int reg = 0; reg < 4; ++reg) {
            int r = r0 + rt*16 + q*4 + reg;
            #pragma unroll
            for (int ct = 0; ct < 4; ++ct) {
                float lv = lembs[(size_t)r*Dd + wv*64 + ct*16 + l15];
                acc[rt][ct][reg] = lv + fmaxf(acc[rt][ct][reg] + bias_c[ct], 0.f);
            }
        }
    }
    // per-wave row partials (s, ss)
    #pragma unroll
    for (int rt = 0; rt < 2; ++rt) {
        #pragma unroll
        for (int reg = 0; reg < 4; ++reg) {
            float s  = ((acc[rt][0][reg] + acc[rt][1][reg]) + (acc[rt][2][reg] + acc[rt][3][reg]));
            float ss = ((acc[rt][0][reg]*acc[rt][0][reg] + acc[rt][1][reg]*acc[rt][1][reg])
                      + (acc[rt][2][reg]*acc[rt][2][reg] + acc[rt][3][reg]*acc[rt][3][reg]));
            s  += __shfl_xor(s, 1);  ss += __shfl_xor(ss, 1);
            s  += __shfl_xor(s, 2);  ss += __shfl_xor(ss, 2);
            s  += __shfl_xor(s, 4);  ss += __shfl_xor(ss, 4);
            s  += __shfl_xor(s, 8);  ss += __shfl_xor(ss, 8);
            if (l15 == 0) {
                int rw = rt*16 + q*4 + reg;
                lsep[wv][rw][0] = s;
                lsep[wv][rw][1] = ss;
            }
        }
    }
    __syncthreads();
    if (tid < 32) {
        float s  = (lsep[0][tid][0] + lsep[1][tid][0]) + (lsep[2][tid][0] + lsep[3][tid][0]);
        float ss = (lsep[0][tid][1] + lsep[1][tid][1]) + (lsep[2][tid][1] + lsep[3][tid][1]);
        float mu = s * (1.f/Dd);
        musig[tid][0] = mu;
        musig[tid][1] = rsqrtf(ss*(1.f/Dd) - mu*mu + EPSf);
    }
    __syncthreads();
    float gl[4], bl[4];
    #pragma unroll
    for (int ct = 0; ct < 4; ++ct) {
        gl[ct] = em_g[wv*64 + ct*16 + l15];
        bl[ct] = em_beta[wv*64 + ct*16 + l15];
    }
    #pragma unroll
    for (int rt = 0; rt < 2; ++rt) {
        #pragma unroll
        for (int reg = 0; reg < 4; ++reg) {
            int rw = rt*16 + q*4 + reg;
            int r = r0 + rw;
            float mu = musig[rw][0], rs = musig[rw][1];
            unsigned short* dst = h_bf + (size_t)r*Dd + wv*64;
            #pragma unroll
            for (int ct = 0; ct < 4; ++ct)
                dst[ct*16 + l15] = f2bf((acc[rt][ct][reg] - mu)*rs*gl[ct] + bl[ct]);
        }
    }
}

// ---------------- K_em (MFMA): C[k][v] = h @ dec_W^T, f32 B-load + in-reg pack ----------------
__global__ __launch_bounds__(256) void k_em_mfma4(
    const float* __restrict__ dec_W, const float* __restrict__ dec_b,
    const unsigned short* __restrict__ h_bf, float* __restrict__ part,
    unsigned short* __restrict__ E2)
{
    int vb = blockIdx.x, kg = blockIdx.y;
    int tid = threadIdx.x, lane = tid & 63, wv = tid >> 6;
    int l15 = lane & 15, q = lane >> 4;
    __shared__ short hs[64][264];

    {
        int row = tid >> 2, c0 = (tid & 3) * 64;
        const short8* src = (const short8*)(h_bf + (size_t)(kg*64 + row)*Dd + c0);
        #pragma unroll
        for (int u = 0; u < 8; ++u)
            *(short8*)&hs[row][c0 + u*8] = src[u];
    }
    __syncthreads();

    const float* bptr[4];
    int vcol[4]; bool vok[4];
    #pragma unroll
    for (int ct = 0; ct < 4; ++ct) {
        int v = vb*256 + wv*64 + ct*16 + l15;
        vok[ct] = (v < Vv);
        if (v > Vv-1) v = Vv-1;
        vcol[ct] = v;
        bptr[ct] = dec_W + (size_t)v*Dd + q*8;
    }
    f32x4 acc[4][4];
    #pragma unroll
    for (int mt = 0; mt < 4; ++mt)
        #pragma unroll
        for (int ct = 0; ct < 4; ++ct)
            acc[mt][ct] = (f32x4){0.f,0.f,0.f,0.f};

    for (int ks = 0; ks < 8; ++ks) {
        short8 a[4], b[4];
        #pragma unroll
        for (int ct = 0; ct < 4; ++ct) {
            float4 f0 = *(const float4*)(bptr[ct] + ks*32);
            float4 f1 = *(const float4*)(bptr[ct] + ks*32 + 4);
            u32x4 pk;
            pk.x = bfpack(f0.x, f0.y);
            pk.y = bfpack(f0.z, f0.w);
            pk.z = bfpack(f1.x, f1.y);
            pk.w = bfpack(f1.z, f1.w);
            b[ct] = __builtin_bit_cast(short8, pk);
        }
        #pragma unroll
        for (int mt = 0; mt < 4; ++mt)
            a[mt] = *(const short8*)&hs[mt*16 + l15][ks*32 + q*8];
        #pragma unroll
        for (int mt = 0; mt < 4; ++mt)
            #pragma unroll
            for (int ct = 0; ct < 4; ++ct)
                acc[mt][ct] = __builtin_amdgcn_mfma_f32_16x16x32_bf16(a[mt], b[ct], acc[mt][ct], 0,0,0);
    }

    #pragma unroll
    for (int ct = 0; ct < 4; ++ct) {
        if (vok[ct]) {
            float db = dec_b[vcol[ct]];
            #pragma unroll
            for (int mt = 0; mt < 4; ++mt)
                #pragma unroll
                for (int reg = 0; reg < 4; ++reg)
                    acc[mt][ct][reg] += db;
        } else {
            #pragma unroll
            for (int mt = 0; mt < 4; ++mt)
                #pragma unroll
                for (int reg = 0; reg < 4; ++reg)
                    acc[mt][ct][reg] = -1e30f;
        }
    }
    #pragma unroll
    for (int mt = 0; mt < 4; ++mt) {
        #pragma unroll
        for (int reg = 0; reg < 4; ++reg) {
            int k = kg*64 + mt*16 + q*4 + reg;
            unsigned short* dst = E2 + (size_t)k*VPAD + vb*256 + wv*64;
            #pragma unroll
            for (int ct = 0; ct < 4; ++ct)
                if (vok[ct]) dst[ct*16 + l15] = f2bf(acc[mt][ct][reg]);
        }
    }
    #pragma unroll
    for (int mt = 0; mt < 4; ++mt) {
        #pragma unroll
        for (int reg = 0; reg < 4; ++reg) {
            float m = fmaxf(fmaxf(acc[mt][0][reg], acc[mt][1][reg]),
                            fmaxf(acc[mt][2][reg], acc[mt][3][reg]));
            m = fmaxf(m, __shfl_xor(m, 1));
            m = fmaxf(m, __shfl_xor(m, 2));
            m = fmaxf(m, __shfl_xor(m, 4));
            m = fmaxf(m, __shfl_xor(m, 8));
            float s = __expf(acc[mt][0][reg] - m) + __expf(acc[mt][1][reg] - m)
                    + __expf(acc[mt][2][reg] - m) + __expf(acc[mt][3][reg] - m);
            s += __shfl_xor(s, 1);
            s += __shfl_xor(s, 2);
            s += __shfl_xor(s, 4);
            s += __shfl_xor(s, 8);
            if (l15 == 0) {
                int k = kg*64 + mt*16 + q*4 + reg;
                part[((size_t)k*VB3 + vb*4 + wv)*2]     = m;
                part[((size_t)k*VB3 + vb*4 + wv)*2 + 1] = s;
            }
        }
    }
}

// ---------------- K_comb: combine partials -> lse_em[k] ----------------
__global__ __launch_bounds__(64) void k_em_comb3(
    const float* __restrict__ part, float* __restrict__ lse_em)
{
    int k = blockIdx.x, lane = threadIdx.x;
    float m = -1e30f, s = 0.f;
    for (int vb = lane; vb < VB3; vb += 64) {
        float m2 = part[((size_t)k*VB3+vb)*2], s2 = part[((size_t)k*VB3+vb)*2+1];
        if (m2 > m) { s = s*__expf(m - m2) + s2; m = m2; }
        else          s += s2*__expf(m2 - m);
    }
    #pragma unroll
    for (int d = 1; d < 64; d <<= 1) {
        float mo = __shfl_xor(m, d), so = __shfl_xor(s, d);
        float mn = fmaxf(m, mo);
        s = s*__expf(m - mn) + so*__expf(mo - mn);
        m = mn;
    }
    if (lane == 0) lse_em[k] = m + logf(s);
}

// ---------------- K_trans8: 4-barrier, zero-LDS epilogue, direct Td stores ----------------
__global__ __launch_bounds__(256) void k_trans8(
    const float* __restrict__ tlembs, const float* __restrict__ P0,
    const float* __restrict__ P1, const float* __restrict__ tm_bias,
    const short* __restrict__ tdwg_bf, const float* __restrict__ Gt,
    const float* __restrict__ Bt, float* __restrict__ lse_t,
    unsigned short* __restrict__ Td)
{
    __shared__ short th[32][520];
    __shared__ float rstat[32][18];
    __shared__ float musig[32][2];
    __shared__ float lsep[4][32][2];
    int tid = threadIdx.x, lane = tid & 63, wv = tid >> 6;
    int r0 = blockIdx.x * 32;

    {
        const float4* bias0 = (const float4*)tm_bias;
        const float4* bias1 = (const float4*)(tm_bias + 256);
        float4 c0 = bias0[lane], c1 = bias1[lane];
        for (int i = 0; i < 8; ++i) {
            int row = wv*8 + i;
            int r = r0 + row; if (r >= NROWS) r = NROWS - 1;
            int i0 = r / KP1, i1 = r - i0*KP1;
            float4 a0 = ((const float4*)(P0 + (size_t)i0*MD))[lane];
            float4 b0 = ((const float4*)(P1 + (size_t)i1*MD))[lane];
            float4 t0 = ((const float4*)(tlembs + (size_t)i0*Dd))[lane];
            float4 a1 = ((const float4*)(P0 + (size_t)i0*MD + 256))[lane];
            float4 b1 = ((const float4*)(P1 + (size_t)i1*MD + 256))[lane];
            float4 t1 = ((const float4*)(tlembs + (size_t)i1*Dd))[lane];
            float v0 = t0.x + fmaxf(a0.x+b0.x+c0.x, 0.f);
            float v1 = t0.y + fmaxf(a0.y+b0.y+c0.y, 0.f);
            float v2 = t0.z + fmaxf(a0.z+b0.z+c0.z, 0.f);
            float v3 = t0.w + fmaxf(a0.w+b0.w+c0.w, 0.f);
            float v4 = t1.x + fmaxf(a1.x+b1.x+c1.x, 0.f);
            float v5 = t1.y + fmaxf(a1.y+b1.y+c1.y, 0.f);
            float v6 = t1.z + fmaxf(a1.z+b1.z+c1.z, 0.f);
            float v7 = t1.w + fmaxf(a1.w+b1.w+c1.w, 0.f);
            u32x2 p0; p0.x = bfpack(v0, v1); p0.y = bfpack(v2, v3);
            u32x2 p1; p1.x = bfpack(v4, v5); p1.y = bfpack(v6, v7);
            *(u32x2*)&th[row][lane*4]       = p0;
            *(u32x2*)&th[row][256 + lane*4] = p1;
        }
    }
    __syncthreads();
    {
        int row = tid & 31, seg = tid >> 5;
        float s = 0.f, ss = 0.f;
        #pragma unroll
        for (int k8 = 0; k8 < 8; ++k8) {
            short8 vv = *(const short8*)&th[row][seg*64 + k8*8];
            #pragma unroll
            for (int e = 0; e < 8; ++e) {
                float f = bf2f((unsigned short)vv[e]);
                s += f; ss += f*f;
            }
        }
        rstat[row][seg]     = s;
        rstat[row][9 + seg] = ss;
    }
    __syncthreads();
    if (tid < 32) {
        float s  = ((rstat[tid][0] + rstat[tid][1]) + (rstat[tid][2] + rstat[tid][3]))
                 + ((rstat[tid][4] + rstat[tid][5]) + (rstat[tid][6] + rstat[tid][7]));
        float ss = ((rstat[tid][9] + rstat[tid][10]) + (rstat[tid][11] + rstat[tid][12]))
                 + ((rstat[tid][13] + rstat[tid][14]) + (rstat[tid][15] + rstat[tid][16]));
        float mu = s * (1.f/MD);
        musig[tid][0] = mu;
        musig[tid][1] = rsqrtf(ss*(1.f/MD) - mu*mu + EPSf);
    }
    __syncthreads();

    int l15 = lane & 15, q = lane >> 4;
    f32x4 acc[2][4];
    #pragma unroll
    for (int rt = 0; rt < 2; ++rt)
        #pragma unroll
        for (int ct = 0; ct < 4; ++ct)
            acc[rt][ct] = (f32x4){0.f, 0.f, 0.f, 0.f};
    const short* tb = tdwg_bf + ((size_t)(wv*64 + l15))*MD + q*8;
    #pragma unroll 4
    for (int ks = 0; ks < 16; ++ks) {
        int ko = ks*32 + q*8;
        short8 a0 = *(const short8*)&th[ 0 + l15][ko];
        short8 a1 = *(const short8*)&th[16 + l15][ko];
        short8 b0 = *(const short8*)(tb + ks*32);
        short8 b1 = *(const short8*)(tb + 16*MD + ks*32);
        short8 b2 = *(const short8*)(tb + 32*MD + ks*32);
        short8 b3 = *(const short8*)(tb + 48*MD + ks*32);
        acc[0][0] = __builtin_amdgcn_mfma_f32_16x16x32_bf16(a0, b0, acc[0][0], 0,0,0);
        acc[1][0] = __builtin_amdgcn_mfma_f32_16x16x32_bf16(a1, b0, acc[1][0], 0,0,0);
        acc[0][1] = __builtin_amdgcn_mfma_f32_16x16x32_bf16(a0, b1, acc[0][1], 0,0,0);
        acc[1][1] = __builtin_amdgcn_mfma_f32_16x16x32_bf16(a1, b1, acc[1][1], 0,0,0);
        acc[0][2] = __builtin_amdgcn_mfma_f32_16x16x32_bf16(a0, b2, acc[0][2], 0,0,0);
        acc[1][2] = __builtin_amdgcn_mfma_f32_16x16x32_bf16(a1, b2, acc[1][2], 0,0,0);
        acc[0][3] = __builtin_amdgcn_mfma_f32_16x16x32_bf16(a0, b3, acc[0][3], 0,0,0);
        acc[1][3] = __builtin_amdgcn_mfma_f32_16x16x32_bf16(a1, b3, acc[1][3], 0,0,0);
    }

    float Gc[4], Bc[4];
    #pragma unroll
    for (int ct = 0; ct < 4; ++ct) {
        Gc[ct] = Gt[wv*64 + ct*16 + l15];
        Bc[ct] = Bt[wv*64 + ct*16 + l15];
    }
    #pragma unroll
    for (int rt = 0; rt < 2; ++rt) {
        #pragma unroll
        for (int reg = 0; reg < 4; ++reg) {
            int rw = rt*16 + q*4 + reg;
            float mu = musig[rw][0], rs = musig[rw][1];
            #pragma unroll
            for (int ct = 0; ct < 4; ++ct)
                acc[rt][ct][reg] = rs*(acc[rt][ct][reg] - mu*Gc[ct]) + Bc[ct];
        }
    }
    #pragma unroll
    for (int rt = 0; rt < 2; ++rt) {
        #pragma unroll
        for (int reg = 0; reg < 4; ++reg) {
            long r = (long)r0 + rt*16 + q*4 + reg;
            if (r < NROWS) {
                unsigned short* dst = Td + (size_t)r*Kst + wv*64;
                #pragma unroll
                for (int ct = 0; ct < 4; ++ct)
                    dst[ct*16 + l15] = f2bf(acc[rt][ct][reg]);
            }
        }
    }
    #pragma unroll
    for (int rt = 0; rt < 2; ++rt) {
        #pragma unroll
        for (int reg = 0; reg < 4; ++reg) {
            float m = fmaxf(fmaxf(acc[rt][0][reg], acc[rt][1][reg]),
                            fmaxf(acc[rt][2][reg], acc[rt][3][reg]));
            m = fmaxf(m, __shfl_xor(m, 1));
            m = fmaxf(m, __shfl_xor(m, 2));
            m = fmaxf(m, __shfl_xor(m, 4));
            m = fmaxf(m, __shfl_xor(m, 8));
            float s = __expf(acc[rt][0][reg] - m) + __expf(acc[rt][1][reg] - m)
                    + __expf(acc[rt][2][reg] - m) + __expf(acc[rt][3][reg] - m);
            s += __shfl_xor(s, 1);
            s += __shfl_xor(s, 2);
            s += __shfl_xor(s, 4);
            s += __shfl_xor(s, 8);
            if (l15 == 0) {
                int rw = rt*16 + q*4 + reg;
                lsep[wv][rw][0] = m;
                lsep[wv][rw][1] = s;
            }
        }
    }
    __syncthreads();
    if (tid < 32) {
        int r = r0 + tid;
        if (r < NROWS) {
            float m0 = lsep[0][tid][0], m1 = lsep[1][tid][0];
            float m2 = lsep[2][tid][0], m3 = lsep[3][tid][0];
            float mg = fmaxf(fmaxf(m0, m1), fmaxf(m2, m3));
            float s = lsep[0][tid][1]*__expf(m0-mg) + lsep[1][tid][1]*__expf(m1-mg)
                    + lsep[2][tid][1]*__expf(m2-mg) + lsep[3][tid][1]*__expf(m3-mg);
            lse_t[r] = mg + logf(s);
        }
    }
}

// ---------------- K_gather: 2 table lookups per (t,b), one block per t ----------------
__global__ __launch_bounds__(256) void k_gather2(
    const int* __restrict__ x, const int* __restrict__ z,
    const unsigned short* __restrict__ E2, const float* __restrict__ lse_em,
    const unsigned short* __restrict__ Td, const float* __restrict__ lse_t,
    float* __restrict__ out)
{
    int b = threadIdx.x;
    int t = blockIdx.x;
    int zc = z[t*Bb + b];
    int xv = x[t*Bb + b];
    int i0 = (t >= 2) ? z[(t-2)*Bb + b] : Kst;
    int i1 = (t >= 1) ? z[(t-1)*Bb + b] : Kst;
    int lin = i0*KP1 + i1;
    float em = bf2f(E2[(size_t)zc*VPAD + xv]) - lse_em[zc];
    float tr = bf2f(Td[(size_t)lin*Kst + zc]) - lse_t[lin];
    atomicAdd(&out[b], em + tr);
}

extern "C" void kernel_launch(void* const* d_in, const int* in_sizes, int n_in,
                              void* d_out, int out_size, void* d_ws, size_t ws_size,
                              hipStream_t stream)
{
    const int*   x       = (const int*)  d_in[0];
    const int*   z       = (const int*)  d_in[1];
    const float* lembs   = (const float*)d_in[2];
    const float* tlembs  = (const float*)d_in[3];
    const float* dec_W   = (const float*)d_in[4];
    const float* dec_b   = (const float*)d_in[5];
    const float* em_W    = (const float*)d_in[6];
    const float* em_bias = (const float*)d_in[7];
    const float* em_g    = (const float*)d_in[8];
    const float* em_beta = (const float*)d_in[9];
    const float* td_W    = (const float*)d_in[10];
    const float* td_b    = (const float*)d_in[11];
    const float* tm_W    = (const float*)d_in[12];
    const float* tm_bias = (const float*)d_in[13];
    const float* tn_g    = (const float*)d_in[14];
    const float* tn_beta = (const float*)d_in[15];
    float* out = (float*)d_out;

    float* ws     = (float*)d_ws;
    float* P0     = ws;                    // 131584
    float* P1     = P0 + 131584;           // 131584
    float* lse_em = P1 + 131584;           // 256
    float* part   = lse_em + 256;          // 256*784*2 = 401408
    float* lse_t  = part + 401408;         // 66052
    float* Gt     = lse_t + 66052;         // 256
    float* Bt     = Gt + 256;              // 256
    unsigned short* tdwg_bf = (unsigned short*)(Bt + 256);      // 131072 ushort
    unsigned short* h_bf   = tdwg_bf + 131072;                  // 65536 ushort
    unsigned short* E2     = h_bf + 65536;                      // 256*50176 ushort (25.7MB)
    unsigned short* Td     = E2 + (size_t)Kst*VPAD;             // 66049*256 ushort (33.8MB)

    hipMemsetAsync(out, 0, Bb*sizeof(float), stream);
    k_hP<<<108, 256, 0, stream>>>(lembs, em_W, em_bias, em_g, em_beta, h_bf,
                                  tlembs, tm_W, P0, P1,
                                  td_W, tn_g, tn_beta, td_b, tdwg_bf, Gt, Bt);
    k_em_mfma4<<<dim3(VB2, 4), 256, 0, stream>>>(dec_W, dec_b, h_bf, part, E2);
    k_em_comb3<<<Kst, 64, 0, stream>>>(part, lse_em);
    k_trans8<<<(NROWS + 31)/32, 256, 0, stream>>>(tlembs, P0, P1, tm_bias,
                                                  (const short*)tdwg_bf, Gt, Bt,
                                                  lse_t, Td);
    k_gather2<<<Tt, 256, 0, stream>>>(x, z, E2, lse_em, Td, lse_t, out);
}